// Round 8
// baseline (174.987 us; speedup 1.0000x reference)
//
#include <hip/hip_runtime.h>
#include <hip/hip_bf16.h>

// B=2, M=2048, HID=1024, NH=16, D=64.  No softmax in the reference, so
//   out = ((h Wq^T)(h Wk^T)^T (h Wv^T)) Wo^T
// reassociates three times:
//   S_{b,h} = K_h^T V_h                      (64x64 per head)
//   T_b[j,n] = fold of S with Wo             (t_kernel, stored transposed Tt)
//   U_b = Wq^T T_b  =>  out_b = h_b @ U_b    (Wq folded right, Q never formed)
// Computed as Ut_b = Tt_b @ WqT (NT GEMM), then out = hb @ Ut_b^T (NT GEMM).
//
// Dtypes: inputs fp32, d_out fp32; internal bf16 with fp32 accumulate
// (rounds 3-7: absmax 4.0 vs threshold 11.68).
//
// Round-8 deltas: (a) Q folded out of the projection GEMM (N 3072->2048,
// -8.6 GF); (b) new tiny u_gemm Ut = Tt @ WqT (4.3 GF); (c) WqT bf16
// transpose fused into prep; (d) gemm templated on BN, final GEMM uses
// BN=64 -> 512 blocks = 2/CU (was 1/CU); batch via blockIdx.z offsets.
// Lessons kept: no dense-reduction atomics (r6); XOR-swizzled LDS + BK=64 (r6).

typedef unsigned short u16;
typedef unsigned int u32;
typedef __attribute__((ext_vector_type(8))) short bf16x8;
typedef __attribute__((ext_vector_type(4))) float f32x4;

__device__ __forceinline__ void async_copy16(void* lds, const void* g) {
  __builtin_amdgcn_global_load_lds((const __attribute__((address_space(1))) void*)g,
                                   (__attribute__((address_space(3))) void*)lds,
                                   16, 0, 0);
}

__device__ __forceinline__ u16 f2bf(float f) {
  union { __hip_bfloat16 h; u16 u; } c;
  c.h = __float2bfloat16(f);
  return c.u;
}
__device__ __forceinline__ float bflo(u32 w) {
  union { u32 u; float f; } c; c.u = w << 16; return c.f;
}
__device__ __forceinline__ float bfhi(u32 w) {
  union { u32 u; float f; } c; c.u = w & 0xFFFF0000u; return c.f;
}
__device__ __forceinline__ ushort4 cvt4(float4 v) {
  ushort4 o; o.x = f2bf(v.x); o.y = f2bf(v.y); o.z = f2bf(v.z); o.w = f2bf(v.w);
  return o;
}

// ---------------------------------------------------------------- prep ------
// Blocks < 6144: elementwise downcast h->hb, Wk|Wv->wcat2 (block-uniform
// regions).  Blocks 6144..6399: 64x64 LDS-tiled transpose Wq -> WqT (bf16),
// WqT[i*1024+j] = Wq[j*1024+i].
__global__ __launch_bounds__(256) void prep(const float4* __restrict__ h,
                                            const float4* __restrict__ wk,
                                            const float4* __restrict__ wv,
                                            const float* __restrict__ wq,
                                            ushort4* __restrict__ hb,
                                            ushort4* __restrict__ wcat2,
                                            u16* __restrict__ wqt) {
  __shared__ u16 tile[64][72];
  const int t = threadIdx.x;
  if (blockIdx.x < 6144) {
    int i = blockIdx.x * 256 + t;  // float4 units
    if (i < 1048576) { hb[i] = cvt4(h[i]); return; }        // h: 4096x1024
    i -= 1048576;
    if (i < 262144) { wcat2[i] = cvt4(wk[i]); return; }     // K rows 0..1023
    i -= 262144;
    wcat2[262144 + i] = cvt4(wv[i]);                        // V rows 1024..2047
    return;
  }
  const int tb = blockIdx.x - 6144;       // 0..255
  const int j0 = (tb >> 4) * 64;          // source row tile
  const int i0 = (tb & 15) * 64;          // source col tile
  {
    const int jr = t >> 2;                // 0..63
    const int ic = (t & 3) * 16;
    const float* src = wq + (size_t)(j0 + jr) * 1024 + i0 + ic;
    u16* dst = &tile[jr][ic];
#pragma unroll
    for (int w = 0; w < 4; ++w) {
      const float4 v = *(const float4*)(src + 4 * w);
      const ushort4 o = cvt4(v);
      dst[4 * w] = o.x; dst[4 * w + 1] = o.y; dst[4 * w + 2] = o.z; dst[4 * w + 3] = o.w;
    }
  }
  __syncthreads();
  {
    const int ir = t >> 2;                // 0..63 (output row i-local)
    const int jc = (t & 3) * 16;
    u16* dst = wqt + (size_t)(i0 + ir) * 1024 + j0 + jc;
#pragma unroll
    for (int w = 0; w < 16; ++w) dst[w] = tile[jc + w][ir];
  }
}

// ------------------------------------------------------------- NT GEMM ------
// C[z][m,n] = sum_k A[z*zA + m*lda+k] * B[z*zB + n*K+k].  A,B bf16.
// 128 x BN tile (BN=128 or 64), BK=64, 4 waves (2x2), wave 64 x BN/2 via
// 4 x NI of 16x16x32 MFMA (2 k-halves).  LDS XOR swizzle (r6): LDS(row,g)
// holds global 16-B k-group g ^ (row&7); applied on the global-read side so
// global_load_lds dest stays wave-uniform base + lane*16.
template <bool BF16_OUT, int BN>
__global__ __launch_bounds__(256) void gemm_bt(const u16* __restrict__ A, int lda,
                                               const u16* __restrict__ B,
                                               void* __restrict__ Cv,
                                               int N, int K,
                                               size_t zA, size_t zB, size_t zC) {
  constexpr int NI = BN / 32;
  __shared__ u16 Als[128 * 64];
  __shared__ u16 Bls[BN * 64];
  const int t = threadIdx.x;
  const int lane = t & 63;
  const int wave = t >> 6;
  const int wm = (wave >> 1) * 64;
  const int wn = (wave & 1) * (BN / 2);
  const int lrow = lane & 15;      // MFMA m/n index
  const int quad = lane >> 4;      // MFMA k-group (16-B units)
  const int m0 = blockIdx.y * 128;
  const int n0 = blockIdx.x * BN;
  A += (size_t)blockIdx.z * zA;
  B += (size_t)blockIdx.z * zB;

  // staging: copy c covers rows c*32..c*32+31; thread t -> row c*32+(t>>3),
  // LDS group t&7 holding global group (t&7)^((t>>3)&7).
  const int srow = t >> 3;
  const int scol = (((t & 7) ^ (srow & 7)) * 8);
  const u16* Ag0 = A + (size_t)(m0 + srow) * lda + scol;
  const u16* Bg0 = B + (size_t)(n0 + srow) * K + scol;
  u16* Al0 = Als + t * 8;  // + c*2048 u16 per copy (32 rows)
  u16* Bl0 = Bls + t * 8;

  f32x4 acc[4][NI];
#pragma unroll
  for (int i = 0; i < 4; ++i)
#pragma unroll
    for (int j = 0; j < NI; ++j) acc[i][j] = {0.f, 0.f, 0.f, 0.f};

  for (int k0 = 0; k0 < K; k0 += 64) {
#pragma unroll
    for (int c = 0; c < 4; ++c)
      async_copy16(Al0 + c * 2048, Ag0 + (size_t)(c * 32) * lda + k0);
#pragma unroll
    for (int c = 0; c < BN / 32; ++c)
      async_copy16(Bl0 + c * 2048, Bg0 + (size_t)(c * 32) * K + k0);
    __syncthreads();

#pragma unroll
    for (int half = 0; half < 2; ++half) {
      const int gg = quad + half * 4;  // global k-group within BK=64
      bf16x8 af[4], bfv[NI];
#pragma unroll
      for (int i = 0; i < 4; ++i) {
        const int ra = wm + i * 16 + lrow;
        af[i] = *(const bf16x8*)(Als + ra * 64 + ((gg ^ (ra & 7)) << 3));
      }
#pragma unroll
      for (int i = 0; i < NI; ++i) {
        const int rb = wn + i * 16 + lrow;
        bfv[i] = *(const bf16x8*)(Bls + rb * 64 + ((gg ^ (rb & 7)) << 3));
      }
#pragma unroll
      for (int mi = 0; mi < 4; ++mi)
#pragma unroll
        for (int ni = 0; ni < NI; ++ni)
          acc[mi][ni] = __builtin_amdgcn_mfma_f32_16x16x32_bf16(
              af[mi], bfv[ni], acc[mi][ni], 0, 0, 0);
    }
    __syncthreads();
  }

  // C/D layout (verified m89/m91): col = lane&15, row = (lane>>4)*4 + r
  const int crow0 = m0 + wm + (lane >> 4) * 4;
  const int ccol0 = n0 + wn + (lane & 15);
#pragma unroll
  for (int mi = 0; mi < 4; ++mi)
#pragma unroll
    for (int ni = 0; ni < NI; ++ni) {
      const int col = ccol0 + ni * 16;
#pragma unroll
      for (int r = 0; r < 4; ++r) {
        const size_t idx = (size_t)blockIdx.z * zC +
                           (size_t)(crow0 + mi * 16 + r) * N + col;
        if (BF16_OUT) ((u16*)Cv)[idx]   = f2bf(acc[mi][ni][r]);
        else          ((float*)Cv)[idx] = acc[mi][ni][r];
      }
    }
}

// --------------------------------------------- Spart = partial K^T V --------
// KVb: (4096, 2048) bf16; cols [0,1024)=K [1024,2048)=V.
// grid (32 bh, 16 chunks of 128 rows); 64-row LDS stages; each block writes
// its private 64x64 partial to Spart[bh*16 + chunk] with plain stores (r7:
// never atomics for dense reductions).
__global__ __launch_bounds__(256) void s_kernel(const u16* __restrict__ KV,
                                                float* __restrict__ Spart) {
  const int bh = blockIdx.x;
  const int b = bh >> 4, hh = bh & 15;
  const int row0 = b * 2048 + blockIdx.y * 128;
  const u16* Kg = KV + (size_t)row0 * 2048 + hh * 64;

  __shared__ float Ks[64][64];
  __shared__ float Vs[64][64];
  const int t = threadIdx.x;
  const int lr = t >> 2;        // 0..63 row within stage
  const int lc = (t & 3) * 16;  // col group (16 cols)
  const int d1 = (t >> 4) * 4;
  const int d2 = (t & 15) * 4;

  float acc[4][4] = {};

  for (int r0 = 0; r0 < 128; r0 += 64) {
    const u16* kp = Kg + (size_t)(r0 + lr) * 2048 + lc;
    const uint4 kw0 = *(const uint4*)kp;
    const uint4 kw1 = *(const uint4*)(kp + 8);
    const uint4 vw0 = *(const uint4*)(kp + 1024);  // V = K + 1024 cols
    const uint4 vw1 = *(const uint4*)(kp + 1032);
    __syncthreads();  // prev-iter readers done
    float* kd = &Ks[lr][lc];
    *(float4*)(kd)      = float4{bflo(kw0.x), bfhi(kw0.x), bflo(kw0.y), bfhi(kw0.y)};
    *(float4*)(kd + 4)  = float4{bflo(kw0.z), bfhi(kw0.z), bflo(kw0.w), bfhi(kw0.w)};
    *(float4*)(kd + 8)  = float4{bflo(kw1.x), bfhi(kw1.x), bflo(kw1.y), bfhi(kw1.y)};
    *(float4*)(kd + 12) = float4{bflo(kw1.z), bfhi(kw1.z), bflo(kw1.w), bfhi(kw1.w)};
    float* vd = &Vs[lr][lc];
    *(float4*)(vd)      = float4{bflo(vw0.x), bfhi(vw0.x), bflo(vw0.y), bfhi(vw0.y)};
    *(float4*)(vd + 4)  = float4{bflo(vw0.z), bfhi(vw0.z), bflo(vw0.w), bfhi(vw0.w)};
    *(float4*)(vd + 8)  = float4{bflo(vw1.x), bfhi(vw1.x), bflo(vw1.y), bfhi(vw1.y)};
    *(float4*)(vd + 12) = float4{bflo(vw1.z), bfhi(vw1.z), bflo(vw1.w), bfhi(vw1.w)};
    __syncthreads();
#pragma unroll
    for (int r = 0; r < 64; ++r) {
      float kv[4], vv[4];
      *(float4*)kv = *(const float4*)&Ks[r][d1];
      *(float4*)vv = *(const float4*)&Vs[r][d2];
#pragma unroll
      for (int i = 0; i < 4; ++i)
#pragma unroll
        for (int j = 0; j < 4; ++j) acc[i][j] += kv[i] * vv[j];
    }
  }
  float* Sp = Spart + ((size_t)bh * 16 + blockIdx.y) * 4096;
#pragma unroll
  for (int i = 0; i < 4; ++i)
    *(float4*)&Sp[(d1 + i) * 64 + d2] =
        float4{acc[i][0], acc[i][1], acc[i][2], acc[i][3]};
}

// ---------------------------------------------------- S = sum_c Spart -------
__global__ __launch_bounds__(256) void reduce_s(const float4* __restrict__ Spart,
                                                float4* __restrict__ S) {
  const int g = blockIdx.x * 256 + threadIdx.x;  // 0..32767
  const int bh = g >> 10, j = g & 1023;
  const float4* p = Spart + (size_t)bh * 16384 + j;  // 16 chunks * 1024 f4
  float4 a = {0.f, 0.f, 0.f, 0.f};
#pragma unroll
  for (int c = 0; c < 16; ++c) {
    const float4 v = p[(size_t)c * 1024];
    a.x += v.x; a.y += v.y; a.z += v.z; a.w += v.w;
  }
  S[g] = a;
}

// ------------------------------------------- Tt = (S_h Wo_h^T)^T ------------
// T_b[h*64+d, n] = sum_j S_{b,h}[d,j] * Wo[n, h*64+j];  stored transposed
// (row n, col h*64+d) bf16.  grid (8 n-chunks, 16 heads, 2 batches).
__global__ __launch_bounds__(256) void t_kernel(const float* __restrict__ S,
                                                const float* __restrict__ Wo,
                                                u16* __restrict__ Tt) {
  const int n0 = blockIdx.x * 128;
  const int hh = blockIdx.y;
  const int b  = blockIdx.z;
  __shared__ float Ss[64][68];
  __shared__ float Ws[128][68];
  const int t = threadIdx.x;
  {
    const float* sg = S + (size_t)(b * 16 + hh) * 4096 + (t >> 2) * 64 + (t & 3) * 16;
    float* sd = &Ss[t >> 2][(t & 3) * 16];
#pragma unroll
    for (int i = 0; i < 4; ++i) *(float4*)(sd + 4 * i) = *(const float4*)(sg + 4 * i);
    const float* wg = Wo + (size_t)(n0 + (t >> 1)) * 1024 + hh * 64 + (t & 1) * 32;
    float* wd = &Ws[t >> 1][(t & 1) * 32];
#pragma unroll
    for (int i = 0; i < 8; ++i) *(float4*)(wd + 4 * i) = *(const float4*)(wg + 4 * i);
  }
  __syncthreads();

  const int td = (t >> 4) * 4;  // d = td..td+3
  const int tn = t & 15;        // n = n0 + tn + 16k
  float acc[4][8] = {};
  for (int jj = 0; jj < 64; jj += 4) {
    float4 sv[4], wv[8];
#pragma unroll
    for (int i = 0; i < 4; ++i) sv[i] = *(const float4*)&Ss[td + i][jj];
#pragma unroll
    for (int k = 0; k < 8; ++k) wv[k] = *(const float4*)&Ws[tn + 16 * k][jj];
#pragma unroll
    for (int i = 0; i < 4; ++i)
#pragma unroll
      for (int k = 0; k < 8; ++k)
        acc[i][k] += sv[i].x * wv[k].x + sv[i].y * wv[k].y +
                     sv[i].z * wv[k].z + sv[i].w * wv[k].w;
  }

  u16* tp = Tt + (size_t)b * 1048576;
#pragma unroll
  for (int k = 0; k < 8; ++k) {
    const int n = n0 + tn + 16 * k;
    ushort4 o;
    o.x = f2bf(acc[0][k]); o.y = f2bf(acc[1][k]);
    o.z = f2bf(acc[2][k]); o.w = f2bf(acc[3][k]);
    *(ushort4*)&tp[(size_t)n * 1024 + hh * 64 + td] = o;
  }
}

// ---------------------------------------------------------------------------
extern "C" void kernel_launch(void* const* d_in, const int* in_sizes, int n_in,
                              void* d_out, int out_size, void* d_ws, size_t ws_size,
                              hipStream_t stream) {
  const float* h  = (const float*)d_in[0];  // (4096, 1024) fp32
  // d_in[1] = key_pe: dead branch in reference, unused.
  const float* Wq = (const float*)d_in[2];
  const float* Wk = (const float*)d_in[3];
  const float* Wv = (const float*)d_in[4];
  const float* Wo = (const float*)d_in[5];

  char* ws = (char*)d_ws;
  u16*   hb    = (u16*)(ws);                    // 4096*1024*2 = 8 MiB @ 0
  u16*   wcat2 = (u16*)(ws + (8ull  << 20));    // 2048*1024*2 = 4 MiB
  u16*   wqt   = (u16*)(ws + (12ull << 20));    // 1024*1024*2 = 2 MiB
  u16*   KVb   = (u16*)(ws + (16ull << 20));    // 4096*2048*2 = 16 MiB
  float* S     = (float*)(ws + (32ull << 20));  // 32*64*64*4  = 0.5 MiB
  u16*   Tt    = (u16*)(ws + (33ull << 20));    // 2*1024*1024*2 = 4 MiB
  u16*   Ut    = (u16*)(ws + (37ull << 20));    // 2*1024*1024*2 = 4 MiB
  float* Spart = (float*)(ws + (41ull << 20));  // 512*64*64*4 = 8 MiB
  // total ws use: 49 MiB (ws_size = 256 MiB)

  prep<<<6400, 256, 0, stream>>>((const float4*)h, (const float4*)Wk,
                                 (const float4*)Wv, Wq,
                                 (ushort4*)hb, (ushort4*)wcat2, wqt);
  // KVb = hb @ wcat2^T : (4096 x 2048), K=1024
  gemm_bt<true, 128><<<dim3(16, 32, 1), 256, 0, stream>>>(
      hb, 1024, wcat2, KVb, 2048, 1024, 0, 0, 0);
  s_kernel<<<dim3(32, 16), 256, 0, stream>>>(KVb, Spart);
  reduce_s<<<128, 256, 0, stream>>>((const float4*)Spart, (float4*)S);
  t_kernel<<<dim3(8, 16, 2), 256, 0, stream>>>(S, Wo, Tt);
  // Ut_b = Tt_b @ WqT : (1024 x 1024) per batch, K=1024
  gemm_bt<true, 128><<<dim3(8, 8, 2), 256, 0, stream>>>(
      Tt, 1024, wqt, Ut, 1024, 1024, 1048576, 0, 1048576);
  // out_b = hb_b @ Ut_b^T : (2048 x 1024) per batch, K=1024
  gemm_bt<false, 64><<<dim3(16, 16, 2), 256, 0, stream>>>(
      hb, 1024, Ut, d_out, 1024, 1024,
      (size_t)2048 * 1024, 1048576, (size_t)2048 * 1024);
}

// Round 9
// 158.855 us; speedup vs baseline: 1.1016x; 1.1016x over previous
//
#include <hip/hip_runtime.h>
#include <hip/hip_bf16.h>

// B=2, M=2048, HID=1024, NH=16, D=64.  No softmax in the reference, so
//   out = ((h Wq^T)(h Wk^T)^T (h Wv^T)) Wo^T
// reassociates twice:  S_{b,h} = K_h^T V_h  (64x64), and
//   out_b = Q_b @ T_b   with  T_b[h*64+d, n] = sum_j S_{b,h}[d,j] Wo[n, h*64+j]
//
// Dtypes: inputs fp32, d_out fp32; internal bf16 with fp32 accumulate
// (rounds 3-8: absmax 3-4 vs threshold 11.68).
//
// Round-9: revert round-8's Q-fold (regressed +12us: u_gemm ran at 0.5
// blocks/CU and BN=64 halved gemm2's compute/staging ratio — FLOPs deleted
// at high occupancy reappeared at low occupancy).  Back to r7 structure
// (163us) with ONE change: gemm2 tile 128x128 -> 64x128, grid (8,64) = 512
// blocks = 2/CU (was 1/CU).  BM is the halved dim so the L2-resident B (Tt,
// 2MB/batch, re-read 16x) keeps full 128-width tiles; streamed-once A pays.
// Lessons kept: no dense-reduction atomics (r6->r7); XOR swizzle + BK=64 (r6).
//
// Pipeline:
//   0. prep: h->hb (bf16), Wq|Wk|Wv->wcat (bf16)
//   1. QKVb = hb @ wcat^T        (4096x3072 bf16)            [MFMA GEMM]
//   2. Spart[bh,c] = K^T V partial over 128 rows             [VALU]
//   2b. S = sum_c Spart                                      [BW]
//   3. Tt[b][n,k] = (S_h Wo_h^T)^T  (2 x 1024x1024 bf16)     [VALU]
//   4. out = Q @ Tt_b^T          (4096x1024 fp32 -> d_out)   [MFMA GEMM]

typedef unsigned short u16;
typedef unsigned int u32;
typedef __attribute__((ext_vector_type(8))) short bf16x8;
typedef __attribute__((ext_vector_type(4))) float f32x4;

__device__ __forceinline__ void async_copy16(void* lds, const void* g) {
  __builtin_amdgcn_global_load_lds((const __attribute__((address_space(1))) void*)g,
                                   (__attribute__((address_space(3))) void*)lds,
                                   16, 0, 0);
}

__device__ __forceinline__ u16 f2bf(float f) {
  union { __hip_bfloat16 h; u16 u; } c;
  c.h = __float2bfloat16(f);
  return c.u;
}
__device__ __forceinline__ float bflo(u32 w) {
  union { u32 u; float f; } c; c.u = w << 16; return c.f;
}
__device__ __forceinline__ float bfhi(u32 w) {
  union { u32 u; float f; } c; c.u = w & 0xFFFF0000u; return c.f;
}
__device__ __forceinline__ ushort4 cvt4(float4 v) {
  ushort4 o; o.x = f2bf(v.x); o.y = f2bf(v.y); o.z = f2bf(v.z); o.w = f2bf(v.w);
  return o;
}

// ---------------------------------------------------------------- prep ------
// h->hb, Wq|Wk|Wv->wcat (bf16).  Region bounds are multiples of 256 float4s
// -> block-uniform branches.
__global__ __launch_bounds__(256) void prep(const float4* __restrict__ h,
                                            const float4* __restrict__ wq,
                                            const float4* __restrict__ wk,
                                            const float4* __restrict__ wv,
                                            ushort4* __restrict__ hb,
                                            ushort4* __restrict__ wcat) {
  int i = blockIdx.x * 256 + threadIdx.x;  // float4 units
  if (i < 1048576) { hb[i] = cvt4(h[i]); return; }          // h: 4096x1024
  i -= 1048576;
  if (i < 262144) { wcat[i] = cvt4(wq[i]); return; }
  i -= 262144;
  if (i < 262144) { wcat[262144 + i] = cvt4(wk[i]); return; }
  i -= 262144;
  wcat[524288 + i] = cvt4(wv[i]);
}

// ------------------------------------------------------------- NT GEMM ------
// C[m,n] = sum_k A[m*lda+k] * B[n*K+k].  A,B bf16.  BM x BN tile, BK=64,
// 4 waves arranged (BM/64) x (4/(BM/64)); each wave 64 x BN/WC via
// 4 x NI of 16x16x32 MFMA (2 k-halves).  LDS XOR swizzle (r6): LDS(row,g)
// holds global 16-B k-group g ^ (row&7); applied on the global-read side so
// global_load_lds dest stays wave-uniform base + lane*16.
// If B1 != nullptr, row-blocks with m0 >= 2048 use B1 (per-batch T).
template <bool BF16_OUT, int BM, int BN>
__global__ __launch_bounds__(256) void gemm_bt(const u16* __restrict__ A, int lda,
                                               const u16* __restrict__ B0,
                                               const u16* __restrict__ B1,
                                               void* __restrict__ Cv,
                                               int N, int K) {
  constexpr int WR = BM / 64;       // wave rows (2 or 1)
  constexpr int WC = 4 / WR;        // wave cols (2 or 4)
  constexpr int NI = BN / WC / 16;  // 16-col MFMA tiles per wave
  __shared__ u16 Als[BM * 64];
  __shared__ u16 Bls[BN * 64];
  const int t = threadIdx.x;
  const int lane = t & 63;
  const int wave = t >> 6;
  const int wm = (wave / WC) * 64;
  const int wn = (wave % WC) * (BN / WC);
  const int lrow = lane & 15;      // MFMA m/n index
  const int quad = lane >> 4;      // MFMA k-group (16-B units)
  const int m0 = blockIdx.y * BM;
  const int n0 = blockIdx.x * BN;
  const u16* B = (B1 != nullptr && m0 >= 2048) ? B1 : B0;

  // staging: copy c covers rows c*32..c*32+31; thread t -> row c*32+(t>>3),
  // LDS group t&7 holding global group (t&7)^((t>>3)&7).
  const int srow = t >> 3;
  const int scol = (((t & 7) ^ (srow & 7)) * 8);
  const u16* Ag0 = A + (size_t)(m0 + srow) * lda + scol;
  const u16* Bg0 = B + (size_t)(n0 + srow) * K + scol;
  u16* Al0 = Als + t * 8;  // + c*2048 u16 per copy (32 rows)
  u16* Bl0 = Bls + t * 8;

  f32x4 acc[4][NI];
#pragma unroll
  for (int i = 0; i < 4; ++i)
#pragma unroll
    for (int j = 0; j < NI; ++j) acc[i][j] = {0.f, 0.f, 0.f, 0.f};

  for (int k0 = 0; k0 < K; k0 += 64) {
#pragma unroll
    for (int c = 0; c < BM / 32; ++c)
      async_copy16(Al0 + c * 2048, Ag0 + (size_t)(c * 32) * lda + k0);
#pragma unroll
    for (int c = 0; c < BN / 32; ++c)
      async_copy16(Bl0 + c * 2048, Bg0 + (size_t)(c * 32) * K + k0);
    __syncthreads();

#pragma unroll
    for (int half = 0; half < 2; ++half) {
      const int gg = quad + half * 4;  // global k-group within BK=64
      bf16x8 af[4], bfv[NI];
#pragma unroll
      for (int i = 0; i < 4; ++i) {
        const int ra = wm + i * 16 + lrow;
        af[i] = *(const bf16x8*)(Als + ra * 64 + ((gg ^ (ra & 7)) << 3));
      }
#pragma unroll
      for (int i = 0; i < NI; ++i) {
        const int rb = wn + i * 16 + lrow;
        bfv[i] = *(const bf16x8*)(Bls + rb * 64 + ((gg ^ (rb & 7)) << 3));
      }
#pragma unroll
      for (int mi = 0; mi < 4; ++mi)
#pragma unroll
        for (int ni = 0; ni < NI; ++ni)
          acc[mi][ni] = __builtin_amdgcn_mfma_f32_16x16x32_bf16(
              af[mi], bfv[ni], acc[mi][ni], 0, 0, 0);
    }
    __syncthreads();
  }

  // C/D layout (verified m89/m91): col = lane&15, row = (lane>>4)*4 + r
  const int crow0 = m0 + wm + (lane >> 4) * 4;
  const int ccol0 = n0 + wn + (lane & 15);
#pragma unroll
  for (int mi = 0; mi < 4; ++mi)
#pragma unroll
    for (int ni = 0; ni < NI; ++ni) {
      const int col = ccol0 + ni * 16;
#pragma unroll
      for (int r = 0; r < 4; ++r) {
        const size_t idx = (size_t)(crow0 + mi * 16 + r) * N + col;
        if (BF16_OUT) ((u16*)Cv)[idx]   = f2bf(acc[mi][ni][r]);
        else          ((float*)Cv)[idx] = acc[mi][ni][r];
      }
    }
}

// --------------------------------------------- Spart = partial K^T V --------
// QKVb: (4096, 3072) bf16; cols [0,1024)=Q [1024,2048)=K [2048,3072)=V.
// grid (32 bh, 16 chunks of 128 rows); 64-row LDS stages; each block writes
// its private 64x64 partial to Spart[bh*16 + chunk] with plain stores.
__global__ __launch_bounds__(256) void s_kernel(const u16* __restrict__ QKV,
                                                float* __restrict__ Spart) {
  const int bh = blockIdx.x;
  const int b = bh >> 4, hh = bh & 15;
  const int row0 = b * 2048 + blockIdx.y * 128;
  const u16* Kg = QKV + (size_t)row0 * 3072 + 1024 + hh * 64;

  __shared__ float Ks[64][64];
  __shared__ float Vs[64][64];
  const int t = threadIdx.x;
  const int lr = t >> 2;        // 0..63 row within stage
  const int lc = (t & 3) * 16;  // col group (16 cols)
  const int d1 = (t >> 4) * 4;
  const int d2 = (t & 15) * 4;

  float acc[4][4] = {};

  for (int r0 = 0; r0 < 128; r0 += 64) {
    const u16* kp = Kg + (size_t)(r0 + lr) * 3072 + lc;
    const uint4 kw0 = *(const uint4*)kp;
    const uint4 kw1 = *(const uint4*)(kp + 8);
    const uint4 vw0 = *(const uint4*)(kp + 1024);  // V = K + 1024 cols
    const uint4 vw1 = *(const uint4*)(kp + 1032);
    __syncthreads();  // prev-iter readers done
    float* kd = &Ks[lr][lc];
    *(float4*)(kd)      = float4{bflo(kw0.x), bfhi(kw0.x), bflo(kw0.y), bfhi(kw0.y)};
    *(float4*)(kd + 4)  = float4{bflo(kw0.z), bfhi(kw0.z), bflo(kw0.w), bfhi(kw0.w)};
    *(float4*)(kd + 8)  = float4{bflo(kw1.x), bfhi(kw1.x), bflo(kw1.y), bfhi(kw1.y)};
    *(float4*)(kd + 12) = float4{bflo(kw1.z), bfhi(kw1.z), bflo(kw1.w), bfhi(kw1.w)};
    float* vd = &Vs[lr][lc];
    *(float4*)(vd)      = float4{bflo(vw0.x), bfhi(vw0.x), bflo(vw0.y), bfhi(vw0.y)};
    *(float4*)(vd + 4)  = float4{bflo(vw0.z), bfhi(vw0.z), bflo(vw0.w), bfhi(vw0.w)};
    *(float4*)(vd + 8)  = float4{bflo(vw1.x), bfhi(vw1.x), bflo(vw1.y), bfhi(vw1.y)};
    *(float4*)(vd + 12) = float4{bflo(vw1.z), bfhi(vw1.z), bflo(vw1.w), bfhi(vw1.w)};
    __syncthreads();
#pragma unroll
    for (int r = 0; r < 64; ++r) {
      float kv[4], vv[4];
      *(float4*)kv = *(const float4*)&Ks[r][d1];
      *(float4*)vv = *(const float4*)&Vs[r][d2];
#pragma unroll
      for (int i = 0; i < 4; ++i)
#pragma unroll
        for (int j = 0; j < 4; ++j) acc[i][j] += kv[i] * vv[j];
    }
  }
  float* Sp = Spart + ((size_t)bh * 16 + blockIdx.y) * 4096;
#pragma unroll
  for (int i = 0; i < 4; ++i)
    *(float4*)&Sp[(d1 + i) * 64 + d2] =
        float4{acc[i][0], acc[i][1], acc[i][2], acc[i][3]};
}

// ---------------------------------------------------- S = sum_c Spart -------
__global__ __launch_bounds__(256) void reduce_s(const float4* __restrict__ Spart,
                                                float4* __restrict__ S) {
  const int g = blockIdx.x * 256 + threadIdx.x;  // 0..32767
  const int bh = g >> 10, j = g & 1023;
  const float4* p = Spart + (size_t)bh * 16384 + j;  // 16 chunks * 1024 f4
  float4 a = {0.f, 0.f, 0.f, 0.f};
#pragma unroll
  for (int c = 0; c < 16; ++c) {
    const float4 v = p[(size_t)c * 1024];
    a.x += v.x; a.y += v.y; a.z += v.z; a.w += v.w;
  }
  S[g] = a;
}

// ------------------------------------------- Tt = (S_h Wo_h^T)^T ------------
// T_b[h*64+d, n] = sum_j S_{b,h}[d,j] * Wo[n, h*64+j];  stored transposed
// (row n, col h*64+d) bf16.  grid (8 n-chunks, 16 heads, 2 batches).
__global__ __launch_bounds__(256) void t_kernel(const float* __restrict__ S,
                                                const float* __restrict__ Wo,
                                                u16* __restrict__ Tt) {
  const int n0 = blockIdx.x * 128;
  const int hh = blockIdx.y;
  const int b  = blockIdx.z;
  __shared__ float Ss[64][68];
  __shared__ float Ws[128][68];
  const int t = threadIdx.x;
  {
    const float* sg = S + (size_t)(b * 16 + hh) * 4096 + (t >> 2) * 64 + (t & 3) * 16;
    float* sd = &Ss[t >> 2][(t & 3) * 16];
#pragma unroll
    for (int i = 0; i < 4; ++i) *(float4*)(sd + 4 * i) = *(const float4*)(sg + 4 * i);
    const float* wg = Wo + (size_t)(n0 + (t >> 1)) * 1024 + hh * 64 + (t & 1) * 32;
    float* wd = &Ws[t >> 1][(t & 1) * 32];
#pragma unroll
    for (int i = 0; i < 8; ++i) *(float4*)(wd + 4 * i) = *(const float4*)(wg + 4 * i);
  }
  __syncthreads();

  const int td = (t >> 4) * 4;  // d = td..td+3
  const int tn = t & 15;        // n = n0 + tn + 16k
  float acc[4][8] = {};
  for (int jj = 0; jj < 64; jj += 4) {
    float4 sv[4], wv[8];
#pragma unroll
    for (int i = 0; i < 4; ++i) sv[i] = *(const float4*)&Ss[td + i][jj];
#pragma unroll
    for (int k = 0; k < 8; ++k) wv[k] = *(const float4*)&Ws[tn + 16 * k][jj];
#pragma unroll
    for (int i = 0; i < 4; ++i)
#pragma unroll
      for (int k = 0; k < 8; ++k)
        acc[i][k] += sv[i].x * wv[k].x + sv[i].y * wv[k].y +
                     sv[i].z * wv[k].z + sv[i].w * wv[k].w;
  }

  u16* tp = Tt + (size_t)b * 1048576;
#pragma unroll
  for (int k = 0; k < 8; ++k) {
    const int n = n0 + tn + 16 * k;
    ushort4 o;
    o.x = f2bf(acc[0][k]); o.y = f2bf(acc[1][k]);
    o.z = f2bf(acc[2][k]); o.w = f2bf(acc[3][k]);
    *(ushort4*)&tp[(size_t)n * 1024 + hh * 64 + td] = o;
  }
}

// ---------------------------------------------------------------------------
extern "C" void kernel_launch(void* const* d_in, const int* in_sizes, int n_in,
                              void* d_out, int out_size, void* d_ws, size_t ws_size,
                              hipStream_t stream) {
  const float* h  = (const float*)d_in[0];  // (4096, 1024) fp32
  // d_in[1] = key_pe: dead branch in reference, unused.
  const float* Wq = (const float*)d_in[2];
  const float* Wk = (const float*)d_in[3];
  const float* Wv = (const float*)d_in[4];
  const float* Wo = (const float*)d_in[5];

  char* ws = (char*)d_ws;
  u16*   hb    = (u16*)(ws);                    // 4096*1024*2 = 8 MiB @ 0
  u16*   wcat  = (u16*)(ws + (8ull  << 20));    // 3072*1024*2 = 6 MiB
  u16*   QKVb  = (u16*)(ws + (16ull << 20));    // 4096*3072*2 = 24 MiB
  float* S     = (float*)(ws + (40ull << 20));  // 32*64*64*4  = 0.5 MiB
  u16*   Tt    = (u16*)(ws + (41ull << 20));    // 2*1024*1024*2 = 4 MiB
  float* Spart = (float*)(ws + (48ull << 20));  // 512*64*64*4 = 8 MiB
  // total ws use: 56 MiB (ws_size = 256 MiB)

  prep<<<7168, 256, 0, stream>>>((const float4*)h, (const float4*)Wq,
                                 (const float4*)Wk, (const float4*)Wv,
                                 (ushort4*)hb, (ushort4*)wcat);
  // QKVb = hb @ wcat^T : (4096 x 3072), K=1024, 768 blocks = 3/CU
  gemm_bt<true, 128, 128><<<dim3(24, 32), 256, 0, stream>>>(
      hb, 1024, wcat, nullptr, QKVb, 3072, 1024);
  s_kernel<<<dim3(32, 16), 256, 0, stream>>>(QKVb, Spart);
  reduce_s<<<128, 256, 0, stream>>>((const float4*)Spart, (float4*)S);
  t_kernel<<<dim3(8, 16, 2), 256, 0, stream>>>(S, Wo, Tt);
  // out = Q @ Tt_b^T : (4096 x 1024), K=1024, BM=64 -> 512 blocks = 2/CU
  gemm_bt<false, 64, 128><<<dim3(8, 64), 256, 0, stream>>>(
      QKVb, 3072, Tt, Tt + 1048576, d_out, 1024, 1024);
}